// Round 14
// baseline (68.543 us; speedup 1.0000x reference)
//
#include <hip/hip_runtime.h>
#include <hip/hip_fp16.h>

#define SPAN 20
#define REPEAT 90

// pred, gt: [4, 1, 512, 512] f32. h_offsets, w_offsets: [90] i32.
// out: scalar f32 = mean |l2norm(pred_rd) - l2norm(gt_rd)| over [B,Hb,Wb,R].
//
// Strategy: pack {p,g} as half2 into d_ws (1 MB/batch -> fits every XCD L2),
// then a no-LDS kernel: 1 px/thread, 90 uniform-offset global loads per pass.
// Global loads use vmcnt (independent of the s_load offsets' lgkmcnt), and
// the compiler pipelines them deeply -- unlike ds_read, which it schedules
// next-to-use (rounds 3-13: stuck ~40us, VGPR=12, latency-bound).

constexpr int W  = 512;
constexpr int Wb = 472;           // 512 - 2*SPAN
constexpr int IMG = W * W;        // 262144 px per batch

typedef unsigned int u32;

static __device__ __forceinline__ u32 packpg(float p, float g) {
    return __builtin_bit_cast(u32, __floats2half2_rn(p, g));
}
static __device__ __forceinline__ __half2 h2(u32 v) {
    return __builtin_bit_cast(__half2, v);
}

// ---- kernel 1: pack pred/gt into {p,g} half2 planes in workspace ----
__global__ __launch_bounds__(256) void pack_kernel(
    const float* __restrict__ pred, const float* __restrict__ gt,
    u32* __restrict__ ws)
{
    const int base = (blockIdx.x * 256 + threadIdx.x) * 4;   // 4 px/thread
    const float4 p = *(const float4*)(pred + base);
    const float4 g = *(const float4*)(gt + base);
    uint4 o;
    o.x = packpg(p.x, g.x);
    o.y = packpg(p.y, g.y);
    o.z = packpg(p.z, g.z);
    o.w = packpg(p.w, g.w);
    *(uint4*)(ws + base) = o;
}

// ---- kernel 2: main loss, no LDS, L2-resident gathers ----
__global__ __launch_bounds__(256) void rd_loss_kernel(
    const u32* __restrict__ ws,
    const int* __restrict__ hoff, const int* __restrict__ woff,
    float* __restrict__ out)
{
    const int t  = threadIdx.x;
    int jj = blockIdx.x * 64 + (t & 63);        // 0..511
    const bool valid = jj < Wb;
    jj = valid ? jj : (Wb - 1);                 // clamp -> safe addresses
    const int ii = blockIdx.y * 4 + (t >> 6);   // 0..471
    const int b  = blockIdx.z;

    const int pix = b * IMG + (SPAN + ii) * W + (SPAN + jj);
    const __half2 c = h2(ws[pix]);

    // ---- pass 1: sum of squares {ssp, ssg}; even/odd accumulators ----
    __half2 sA = __floats2half2_rn(0.f, 0.f), sB = sA;
    #pragma unroll
    for (int r = 0; r < REPEAT; ++r) {
        const int soff = hoff[r] * W + woff[r];   // uniform (SALU, lgkmcnt)
        const __half2 d = __hsub2(c, h2(ws[pix + soff]));  // vmcnt pipeline
        if (r & 1) sB = __hfma2(d, d, sB);
        else       sA = __hfma2(d, d, sA);
    }

    // ---- CSE firewall (rounds 7/8 lesson): forbid carrying all 90 loads
    //      across the rsqrt section (reg blow-up -> scratch spill). ----
    asm volatile("" ::: "memory");

    const float ssp = __half2float(__low2half(sA))  + __half2float(__low2half(sB));
    const float ssg = __half2float(__high2half(sA)) + __half2float(__high2half(sB));

    const float invp = (ssp == 0.f) ? 1.f : rsqrtf(ssp);
    const float invg = (ssg == 0.f) ? 1.f : rsqrtf(ssg);

    // |dp*invp - dg*invg| = invp * |dp - (invg/invp)*dg|
    const __half nr = __float2half(-(invg / invp));

    // ---- pass 2: re-read (L1/L2-hot), op_sel fma + abs-add ----
    __half aA = __float2half(0.f), aB = aA;
    #pragma unroll
    for (int r = 0; r < REPEAT; ++r) {
        const int soff = hoff[r] * W + woff[r];
        const __half2 d = __hsub2(c, h2(ws[pix + soff]));
        const __half s = __hfma(nr, __high2half(d), __low2half(d));
        if (r & 1) aB = __hadd(aB, __habs(s));
        else       aA = __hadd(aA, __habs(s));
    }
    const float l = invp * (__half2float(aA) + __half2float(aB));

    float lsum = valid ? l : 0.f;

    // ---- reduction: wave shuffle -> LDS -> one atomic per block ----
    #pragma unroll
    for (int o = 32; o > 0; o >>= 1) lsum += __shfl_down(lsum, o, 64);

    __shared__ float wsum[4];
    const int lane = t & 63;
    const int wid  = t >> 6;
    if (lane == 0) wsum[wid] = lsum;
    __syncthreads();

    if (t == 0) {
        const float s = wsum[0] + wsum[1] + wsum[2] + wsum[3];
        constexpr float scale = 1.0f / (4.0f * 472.0f * 472.0f * 90.0f);
        atomicAdd(out, s * scale);
    }
}

extern "C" void kernel_launch(void* const* d_in, const int* in_sizes, int n_in,
                              void* d_out, int out_size, void* d_ws, size_t ws_size,
                              hipStream_t stream) {
    const float* pred = (const float*)d_in[0];
    const float* gt   = (const float*)d_in[1];
    const int* hoff   = (const int*)d_in[2];
    const int* woff   = (const int*)d_in[3];
    float* out = (float*)d_out;
    u32* ws = (u32*)d_ws;   // needs 4*512*512*4 B = 4 MB

    // Harness poisons d_out once and never re-poisons between graph replays:
    // zero it on-stream every call (graph-capturable).
    hipMemsetAsync(out, 0, sizeof(float), stream);

    // pack: 4*512*512 px / 4 per thread / 256 per block = 1024 blocks
    pack_kernel<<<dim3(1024), 256, 0, stream>>>(pred, gt, ws);

    // main: (512/64 j-tiles, 472/4 i-tiles, 4 batches)
    rd_loss_kernel<<<dim3(8, 118, 4), 256, 0, stream>>>(ws, hoff, woff, out);
}